// Round 22
// baseline (155.873 us; speedup 1.0000x reference)
//
#include <hip/hip_runtime.h>
#include <math.h>

// Problem constants (b=8, c=2048, e=64, h=8)
#define NTOK 16384
#define EDIM 64
#define HHE  512   // h*e
#define TPB  16    // tokens per block
#define TOKPAD 260 // half2 slots per token row: 256 + 4 pad (16B-aligned rows)

typedef _Float16 half8 __attribute__((ext_vector_type(8)));   // MFMA operand type
typedef __fp16   half2v __attribute__((ext_vector_type(2)));  // builtin V2h type
typedef _Float16 f16x2 __attribute__((ext_vector_type(2)));
typedef float    floatx4 __attribute__((ext_vector_type(4)));

__device__ __forceinline__ half8 cvt8(const float4 a, const float4 b) {
    half8 h;
    h[0] = (_Float16)a.x; h[1] = (_Float16)a.y;
    h[2] = (_Float16)a.z; h[3] = (_Float16)a.w;
    h[4] = (_Float16)b.x; h[5] = (_Float16)b.y;
    h[6] = (_Float16)b.z; h[7] = (_Float16)b.w;
    return h;
}

// fp32 += half2 . half2 (v_dot2_f32_f16)
__device__ __forceinline__ float dot2(half2v a, half2v b, float c) {
#if __has_builtin(__builtin_amdgcn_fdot2)
    return __builtin_amdgcn_fdot2(a, b, c, false);
#else
    return fmaf((float)a[0], (float)b[0], fmaf((float)a[1], (float)b[1], c));
#endif
}
__device__ __forceinline__ half2v pk(float x, float y) {
    return __builtin_amdgcn_cvt_pkrtz(x, y);   // v_cvt_pkrtz_f16_f32 (V2h)
}
union h2u { half2v h; f16x2 f; unsigned int u; };
union uqu { half8 h8; half2v h2[4]; };

// ---- FORCED packed-fp16 VOP3P ops on 32-bit pair registers (inline asm;
// hipcc does not form these from vector types — proven R21/R22 counters).
__device__ __forceinline__ unsigned pka16(unsigned a, unsigned b) {
    unsigned d;
    asm("v_pk_add_f16 %0, %1, %2" : "=v"(d) : "v"(a), "v"(b));
    return d;
}
__device__ __forceinline__ unsigned pkmax16(unsigned a, unsigned b) {
    unsigned d;
    asm("v_pk_max_f16 %0, %1, %2" : "=v"(d) : "v"(a), "v"(b));
    return d;
}
__device__ __forceinline__ unsigned pkmul16(unsigned a, unsigned b) {
    unsigned d;
    asm("v_pk_mul_f16 %0, %1, %2" : "=v"(d) : "v"(a), "v"(b));
    return d;
}
__device__ __forceinline__ unsigned pkrelu16(unsigned x, unsigned z0) {
    return pkmax16(x, z0);   // clamp pair to [0,inf); 0u = +0|+0 fp16 pair
}
__device__ __forceinline__ float dot2u(unsigned a, unsigned b, float c) {
    h2u ua, ub; ua.u = a; ub.u = b;
    return dot2(ua.h, ub.h, c);
}

__device__ __forceinline__ float pgen(float z, float inv) {
    return z > 0.0f ? exp2f(inv * log2f(fmaxf(z, 1e-30f))) : 0.0f;
}

// ---------------------------------------------------------------------------
// Kernel 0: fp32 -> fp16 (RTN cast) for the 4 weight matrices only.
// Wq pre-scaled by (alpha-1)/sqrt(e) so the score scale vanishes downstream.
// ---------------------------------------------------------------------------
__global__ __launch_bounds__(256) void cvt_fp16_kernel(
    const float* __restrict__ Wk, const float* __restrict__ Wq,
    const float* __restrict__ Wv, const float* __restrict__ Wu,
    __fp16* __restrict__ wkh, __fp16* __restrict__ wqh,
    __fp16* __restrict__ wvh, __fp16* __restrict__ wuh,
    const float* alpha_p)
{
    const int z = blockIdx.y;
    const float* src; __fp16* dst;
    float s = 1.0f;
    if      (z == 0) { src = Wk; dst = wkh; }
    else if (z == 1) { src = Wq; dst = wqh; s = (alpha_p[0] - 1.0f) * 0.125f; }
    else if (z == 2) { src = Wv; dst = wvh; }
    else             { src = Wu; dst = wuh; }
    const int idx = (blockIdx.x * 256 + threadIdx.x) * 8;
    float4 a = *(const float4*)(src + idx);
    float4 b = *(const float4*)(src + idx + 4);
    a.x *= s; a.y *= s; a.z *= s; a.w *= s;
    b.x *= s; b.y *= s; b.z *= s; b.w *= s;
    *(half8*)(dst + idx) = cvt8(a, b);
}

// ---------------------------------------------------------------------------
// Kernel 1: FULLY FUSED qkv + entmax-attention + output projection.
// R30: TWO-TOKEN INTERLEAVED consumer. R29 fixed the alloca (traffic
// clean: FETCH 3.5MB, WRITE 4.1MB) but dur stayed ~84us: VALUBusy 61%
// at 2.5 waves/SIMD means ~38% of issue slots are intra-wave stalls
// (bisect reduce->compare->tau chains, LDS b128 latency). Each wave's
// 4 tokens are independent solves — interleave them in PAIRS through
// every consumer phase so every dependency chain has a twin stream to
// fill its stall slots. Bitwise-identical math, reordered. rowhA/B
// stay constant-indexed unrolled arrays (clean-traffic kind); q frags
// stay named scalars (uq0..uq3) — no union arrays (R26-R29 lesson).
// ---------------------------------------------------------------------------

// Register-light general-alpha fallback for one token (never taken at
// alpha=1.5; kept out of the hot path's register frame).
#define GENERAL_TOKEN(T, UQ, ROWH, INVS)                                       \
  {                                                                            \
    const int tg = (T);                                                        \
    const float inv = 1.0f / am1;                                              \
    float mx = -3.4e38f;                                                       \
    for (int j = 0; j < 64; ++j) {                                             \
      uqu u0; u0.h8 = *(const half8*)&kT[tg * TOKPAD + j * 4];                 \
      float d = dot2(UQ.h2[0], u0.h2[0], 0.0f);                                \
      d = dot2(UQ.h2[1], u0.h2[1], d);                                         \
      d = dot2(UQ.h2[2], u0.h2[2], d);                                         \
      d = dot2(UQ.h2[3], u0.h2[3], d);                                         \
      mx = fmaxf(mx, d);                                                       \
    }                                                                          \
    float tau_lo = mx - 1.0f;                                                  \
    float dm = (mx - exp2f(-6.0f * am1)) - tau_lo;                             \
    float f_lo = -1.0f;                                                        \
    for (int j = 0; j < 64; ++j) {                                             \
      uqu u0; u0.h8 = *(const half8*)&kT[tg * TOKPAD + j * 4];                 \
      float d = dot2(UQ.h2[0], u0.h2[0], 0.0f);                                \
      d = dot2(UQ.h2[1], u0.h2[1], d);                                         \
      d = dot2(UQ.h2[2], u0.h2[2], d);                                         \
      d = dot2(UQ.h2[3], u0.h2[3], d);                                         \
      f_lo += pgen(d - tau_lo, inv);                                           \
    }                                                                          \
    float tau_m = tau_lo;                                                      \
    for (int it = 0; it < 30; ++it) {                                          \
      dm *= 0.5f;                                                              \
      tau_m = tau_lo + dm;                                                     \
      float f = -1.0f;                                                         \
      for (int j = 0; j < 64; ++j) {                                           \
        uqu u0; u0.h8 = *(const half8*)&kT[tg * TOKPAD + j * 4];               \
        float d = dot2(UQ.h2[0], u0.h2[0], 0.0f);                              \
        d = dot2(UQ.h2[1], u0.h2[1], d);                                       \
        d = dot2(UQ.h2[2], u0.h2[2], d);                                       \
        d = dot2(UQ.h2[3], u0.h2[3], d);                                       \
        f += pgen(d - tau_m, inv);                                             \
      }                                                                        \
      tau_lo = (f * f_lo >= 0.0f) ? tau_m : tau_lo;                            \
    }                                                                          \
    float s = 0.0f;                                                            \
    for (int j = 0; j < 64; j += 2) {                                          \
      uqu u0, u1;                                                              \
      u0.h8 = *(const half8*)&kT[tg * TOKPAD + j * 4];                         \
      u1.h8 = *(const half8*)&kT[tg * TOKPAD + (j + 1) * 4];                   \
      float d0 = dot2(UQ.h2[0], u0.h2[0], 0.0f);                               \
      float d1 = dot2(UQ.h2[0], u1.h2[0], 0.0f);                               \
      d0 = dot2(UQ.h2[1], u0.h2[1], d0);                                       \
      d1 = dot2(UQ.h2[1], u1.h2[1], d1);                                       \
      d0 = dot2(UQ.h2[2], u0.h2[2], d0);                                       \
      d1 = dot2(UQ.h2[2], u1.h2[2], d1);                                       \
      d0 = dot2(UQ.h2[3], u0.h2[3], d0);                                       \
      d1 = dot2(UQ.h2[3], u1.h2[3], d1);                                       \
      const float p0 = pgen(d0 - tau_m, inv);                                  \
      const float p1 = pgen(d1 - tau_m, inv);                                  \
      s += p0 + p1;                                                            \
      h2u c; c.h = pk(p0, p1);                                                 \
      ROWH[j >> 1] = c.u;                                                      \
    }                                                                          \
    INVS = 1.0f / s;                                                           \
  }

// Two tokens T0/T1 (q frags UQA/UQB) interleaved through every phase.
#define CONSUME2(T0, UQA, T1, UQB)                                             \
  do {                                                                         \
    const int tA = (T0);                                                       \
    const int tB = (T1);                                                       \
    float inv_sumA, inv_sumB;                                                  \
    unsigned rowhA[32], rowhB[32];                                             \
    if (am1 == 0.5f) {                                                         \
      unsigned runmaxA = 0u, runmaxB = 0u;                                     \
      _Pragma("unroll")                                                        \
      for (int j = 0; j < 64; j += 2) {                                        \
        uqu a0u, a1u, b0u, b1u;                                                \
        a0u.h8 = *(const half8*)&kT[tA * TOKPAD + j * 4];                      \
        a1u.h8 = *(const half8*)&kT[tA * TOKPAD + (j + 1) * 4];                \
        b0u.h8 = *(const half8*)&kT[tB * TOKPAD + j * 4];                      \
        b1u.h8 = *(const half8*)&kT[tB * TOKPAD + (j + 1) * 4];                \
        float dA0 = dot2(UQA.h2[0], a0u.h2[0], 0.0f);                          \
        float dA1 = dot2(UQA.h2[0], a1u.h2[0], 0.0f);                          \
        float dB0 = dot2(UQB.h2[0], b0u.h2[0], 0.0f);                          \
        float dB1 = dot2(UQB.h2[0], b1u.h2[0], 0.0f);                          \
        dA0 = dot2(UQA.h2[1], a0u.h2[1], dA0);                                 \
        dA1 = dot2(UQA.h2[1], a1u.h2[1], dA1);                                 \
        dB0 = dot2(UQB.h2[1], b0u.h2[1], dB0);                                 \
        dB1 = dot2(UQB.h2[1], b1u.h2[1], dB1);                                 \
        dA0 = dot2(UQA.h2[2], a0u.h2[2], dA0);                                 \
        dA1 = dot2(UQA.h2[2], a1u.h2[2], dA1);                                 \
        dB0 = dot2(UQB.h2[2], b0u.h2[2], dB0);                                 \
        dB1 = dot2(UQB.h2[2], b1u.h2[2], dB1);                                 \
        dA0 = dot2(UQA.h2[3], a0u.h2[3], dA0);                                 \
        dA1 = dot2(UQA.h2[3], a1u.h2[3], dA1);                                 \
        dB0 = dot2(UQB.h2[3], b0u.h2[3], dB0);                                 \
        dB1 = dot2(UQB.h2[3], b1u.h2[3], dB1);                                 \
        h2u cA, cB;                                                            \
        cA.h = pk(dA0, dA1);                                                   \
        cB.h = pk(dB0, dB1);                                                   \
        rowhA[j >> 1] = cA.u;                                                  \
        rowhB[j >> 1] = cB.u;                                                  \
        runmaxA = (j == 0) ? cA.u : pkmax16(runmaxA, cA.u);                    \
        runmaxB = (j == 0) ? cB.u : pkmax16(runmaxB, cB.u);                    \
      }                                                                        \
      h2u muA, muB;                                                            \
      muA.u = runmaxA; muB.u = runmaxB;                                        \
      const float mxA = fmaxf((float)muA.f[0], (float)muA.f[1]);               \
      const float mxB = fmaxf((float)muB.f[0], (float)muB.f[1]);               \
      float tauA_lo = mxA - 1.0f;                                              \
      float tauB_lo = mxB - 1.0f;                                              \
      const float dm0 = 1.0f - exp2f(-6.0f * am1);                             \
      float dmA = dm0, dmB = dm0;                                              \
      const unsigned z0 = 0u;                                                  \
      const half2v one2 = pk(1.0f, 1.0f);                                      \
      _Pragma("unroll")                                                        \
      for (int it = 0; it < 6; ++it) {                                         \
        dmA *= 0.5f; dmB *= 0.5f;                                              \
        const float tauA_m = tauA_lo + dmA;                                    \
        const float tauB_m = tauB_lo + dmB;                                    \
        h2u ntcA, ntcB;                                                        \
        ntcA.h = pk(-tauA_m, -tauA_m);                                         \
        ntcB.h = pk(-tauB_m, -tauB_m);                                         \
        const unsigned ntA = ntcA.u, ntB = ntcB.u;                             \
        float fA0 = -1.0f, fA1 = 0.0f;                                         \
        float fB0 = -1.0f, fB1 = 0.0f;                                         \
        _Pragma("unroll")                                                      \
        for (int jj = 0; jj < 32; jj += 2) {                                   \
          const unsigned aA0 = pkrelu16(pka16(rowhA[jj + 0], ntA), z0);        \
          const unsigned aA1 = pkrelu16(pka16(rowhA[jj + 1], ntA), z0);        \
          const unsigned aB0 = pkrelu16(pka16(rowhB[jj + 0], ntB), z0);        \
          const unsigned aB1 = pkrelu16(pka16(rowhB[jj + 1], ntB), z0);        \
          fA0 = dot2u(aA0, aA0, fA0);                                          \
          fA1 = dot2u(aA1, aA1, fA1);                                          \
          fB0 = dot2u(aB0, aB0, fB0);                                          \
          fB1 = dot2u(aB1, aB1, fB1);                                          \
        }                                                                      \
        const float fA = fA0 + fA1;                                            \
        const float fB = fB0 + fB1;                                            \
        tauA_lo = (fA >= 0.0f) ? tauA_m : tauA_lo;                             \
        tauB_lo = (fB >= 0.0f) ? tauB_m : tauB_lo;                             \
      }                                                                        \
      float tauA = tauA_lo, tauB = tauB_lo;                                    \
      _Pragma("unroll")                                                        \
      for (int it = 0; it < 2; ++it) {                                         \
        h2u ntcA, ntcB;                                                        \
        ntcA.h = pk(-tauA, -tauA);                                             \
        ntcB.h = pk(-tauB, -tauB);                                             \
        const unsigned ntA = ntcA.u, ntB = ntcB.u;                             \
        float fA0 = -1.0f, fB0 = -1.0f;                                        \
        float sA0 = 0.0f, sB0 = 0.0f;                                          \
        _Pragma("unroll")                                                      \
        for (int jj = 0; jj < 32; ++jj) {                                      \
          const unsigned aA = pkrelu16(pka16(rowhA[jj], ntA), z0);             \
          const unsigned aB = pkrelu16(pka16(rowhB[jj], ntB), z0);             \
          fA0 = dot2u(aA, aA, fA0);                                            \
          fB0 = dot2u(aB, aB, fB0);                                            \
          h2u uaA, uaB; uaA.u = aA; uaB.u = aB;                                \
          sA0 = dot2(uaA.h, one2, sA0);                                        \
          sB0 = dot2(uaB.h, one2, sB0);                                        \
        }                                                                      \
        const float sA = sA0 + 1e-20f;                                         \
        const float sB = sB0 + 1e-20f;                                         \
        tauA = tauA + fmaxf(fA0, 0.0f) * __builtin_amdgcn_rcpf(sA + sA);       \
        tauB = tauB + fmaxf(fB0, 0.0f) * __builtin_amdgcn_rcpf(sB + sB);       \
      }                                                                        \
      {                                                                        \
        h2u ntcA, ntcB;                                                        \
        ntcA.h = pk(-tauA, -tauA);                                             \
        ntcB.h = pk(-tauB, -tauB);                                             \
        const unsigned ntA = ntcA.u, ntB = ntcB.u;                             \
        float sA0 = 0.0f, sB0 = 0.0f;                                          \
        _Pragma("unroll")                                                      \
        for (int jj = 0; jj < 32; ++jj) {                                      \
          const unsigned aA = pkrelu16(pka16(rowhA[jj], ntA), z0);             \
          const unsigned aB = pkrelu16(pka16(rowhB[jj], ntB), z0);             \
          sA0 = dot2u(aA, aA, sA0);                                            \
          sB0 = dot2u(aB, aB, sB0);                                            \
          rowhA[jj] = pkmul16(aA, aA);                                         \
          rowhB[jj] = pkmul16(aB, aB);                                         \
        }                                                                      \
        inv_sumA = __builtin_amdgcn_rcpf(sA0);                                 \
        inv_sumB = __builtin_amdgcn_rcpf(sB0);                                 \
      }                                                                        \
    } else {                                                                   \
      GENERAL_TOKEN(tA, UQA, rowhA, inv_sumA);                                 \
      GENERAL_TOKEN(tB, UQB, rowhB, inv_sumB);                                 \
    }                                                                          \
    _Pragma("unroll")                                                          \
    for (int hh = 0; hh < 2; ++hh) {                                           \
      float accA[4], accB[4];                                                  \
      _Pragma("unroll")                                                        \
      for (int h4 = 0; h4 < 4; ++h4) {                                         \
        const int h = hh * 4 + h4;                                             \
        float a0 = 0.0f, a1 = 0.0f;                                            \
        float b0 = 0.0f, b1 = 0.0f;                                            \
        _Pragma("unroll")                                                      \
        for (int jc = 0; jc < 8; ++jc) {                                       \
          uqu uA, uB;                                                          \
          uA.h8 = *(const half8*)&bufA[tA * TOKPAD + h * 32 + jc * 4];         \
          uB.h8 = *(const half8*)&bufA[tB * TOKPAD + h * 32 + jc * 4];         \
          h2u qA0, qA1, qA2, qA3, qB0, qB1, qB2, qB3;                          \
          qA0.u = rowhA[jc * 4 + 0];                                           \
          qA1.u = rowhA[jc * 4 + 1];                                           \
          qA2.u = rowhA[jc * 4 + 2];                                           \
          qA3.u = rowhA[jc * 4 + 3];                                           \
          qB0.u = rowhB[jc * 4 + 0];                                           \
          qB1.u = rowhB[jc * 4 + 1];                                           \
          qB2.u = rowhB[jc * 4 + 2];                                           \
          qB3.u = rowhB[jc * 4 + 3];                                           \
          a0 = dot2(qA0.h, uA.h2[0], a0);                                      \
          b0 = dot2(qB0.h, uB.h2[0], b0);                                      \
          a1 = dot2(qA1.h, uA.h2[1], a1);                                      \
          b1 = dot2(qB1.h, uB.h2[1], b1);                                      \
          a0 = dot2(qA2.h, uA.h2[2], a0);                                      \
          b0 = dot2(qB2.h, uB.h2[2], b0);                                      \
          a1 = dot2(qA3.h, uA.h2[3], a1);                                      \
          b1 = dot2(qB3.h, uB.h2[3], b1);                                      \
        }                                                                      \
        accA[h4] = a0 + a1;                                                    \
        accB[h4] = b0 + b1;                                                    \
      }                                                                        \
      _Pragma("unroll")                                                        \
      for (int h4 = 0; h4 < 4; ++h4) {                                         \
        resL[tA * 520 + (hh * 4 + h4) * 64 + lane] = (__fp16)(accA[h4] * inv_sumA); \
        resL[tB * 520 + (hh * 4 + h4) * 64 + lane] = (__fp16)(accB[h4] * inv_sumB); \
      }                                                                        \
    }                                                                          \
  } while (0)

__global__ __launch_bounds__(256) void qkv_attn_out_kernel(
    const float* __restrict__ x,
    const __fp16* __restrict__ wkh, const float* __restrict__ bk,
    const __fp16* __restrict__ wqh, const float* __restrict__ bq,
    const __fp16* __restrict__ wvh, const float* __restrict__ bv,
    const __fp16* __restrict__ wuh, const float* __restrict__ bu,
    float* __restrict__ out, const float* alpha_p)
{
    __shared__ __align__(16) half2v bufA[TPB * TOKPAD];  // q -> v overlay
    __shared__ __align__(16) half2v kT[TPB * TOKPAD];    // k -> res overlay

    const int tid  = threadIdx.x;
    const int lane = tid & 63;
    const int w    = tid >> 6;
    const int tok0 = blockIdx.x * TPB;

    const int m    = lane & 15;            // token (B row / MFMA D col)
    const int quad = lane >> 4;

    const float am1   = alpha_p[0] - 1.0f;
    const float s_q   = am1 * 0.125f;      // matches cvt kernel's Wq scale

    // ---- x B-fragments: fp32 load + RTN cast
    const float* xrow = x + (size_t)(tok0 + m) * EDIM + quad * 8;
    half8 bfr[2];
    {
        const float4 a0 = *(const float4*)(xrow);
        const float4 a1 = *(const float4*)(xrow + 4);
        const float4 a2 = *(const float4*)(xrow + 32);
        const float4 a3 = *(const float4*)(xrow + 36);
        bfr[0] = cvt8(a0, a1);
        bfr[1] = cvt8(a2, a3);
    }

    // ---- Phase A: produce k (units 0-3) and q (units 4-7); 2 units/wave.
    #pragma unroll
    for (int uu = 0; uu < 2; ++uu) {
        const int unit = w * 2 + uu;
        const int isq  = unit >> 2;            // 0 = k, 1 = q
        const int col0 = (unit & 3) * 128;
        const __fp16* W   = isq ? wqh : wkh;
        const float* bias = isq ? bq : bk;
        half2v* dstT      = isq ? bufA : kT;
        const float bs    = isq ? s_q : 1.0f;

        #pragma unroll
        for (int ct = 0; ct < 8; ++ct) {
            const int n = col0 + ct * 16 + m;
            const int grow = (n & 7) * 64 + (n >> 3);   // permuted W row (q/k)
            const __fp16* wrow = W + (size_t)grow * EDIM + quad * 8;
            floatx4 acc = (floatx4){0.f, 0.f, 0.f, 0.f};
            #pragma unroll
            for (int kc = 0; kc < 2; ++kc) {
                const half8 af = *(const half8*)(wrow + kc * 32);
                acc = __builtin_amdgcn_mfma_f32_16x16x32_f16(af, bfr[kc], acc, 0, 0, 0);
            }
            // lane's 4 regs = D rows quad*4+0..3, D col = m (token)
            // output rows g(n'): h = 4*(quad&1)+reg, j = col0/8+ct*2+(quad>>1)
            const int hbase = 4 * (quad & 1);
            const int j     = (col0 >> 3) + ct * 2 + (quad >> 1);
            float o0 = fmaf(bias[(hbase + 0) * 64 + j], bs, acc[0]);
            float o1 = fmaf(bias[(hbase + 1) * 64 + j], bs, acc[1]);
            float o2 = fmaf(bias[(hbase + 2) * 64 + j], bs, acc[2]);
            float o3 = fmaf(bias[(hbase + 3) * 64 + j], bs, acc[3]);
            h2u p0, p1;
            p0.h = pk(o0, o1);
            p1.h = pk(o2, o3);
            uint2 st; st.x = p0.u; st.y = p1.u;
            *(uint2*)&dstT[m * TOKPAD + j * 4 + 2 * (quad & 1)] = st;
        }
    }
    __syncthreads();   // #1: q,k fully written

    // ---- hoist this wave's 4 private q rows into NAMED registers
    uqu uq0, uq1, uq2, uq3;
    uq0.h8 = *(const half8*)&bufA[(w * 4 + 0) * TOKPAD + lane * 4];
    uq1.h8 = *(const half8*)&bufA[(w * 4 + 1) * TOKPAD + lane * 4];
    uq2.h8 = *(const half8*)&bufA[(w * 4 + 2) * TOKPAD + lane * 4];
    uq3.h8 = *(const half8*)&bufA[(w * 4 + 3) * TOKPAD + lane * 4];
    __syncthreads();   // #2: all q reads complete before v overwrites bufA

    // ---- Phase B: produce v into bufA; 1 unit/wave (col0 = w*128)
    {
        const int col0 = w * 128;
        #pragma unroll
        for (int ct = 0; ct < 8; ++ct) {
            const int n = col0 + ct * 16 + m;
            const __fp16* wrow = wvh + (size_t)n * EDIM + quad * 8;  // natural row
            floatx4 acc = (floatx4){0.f, 0.f, 0.f, 0.f};
            #pragma unroll
            for (int kc = 0; kc < 2; ++kc) {
                const half8 af = *(const half8*)(wrow + kc * 32);
                acc = __builtin_amdgcn_mfma_f32_16x16x32_f16(af, bfr[kc], acc, 0, 0, 0);
            }
            // natural: cols nn..nn+3 = v[h][jj..jj+3]
            const int nn = col0 + ct * 16 + quad * 4;
            const int h  = nn >> 6;
            const int jj = nn & 63;
            const float4 b4 = *(const float4*)&bv[nn];
            h2u p0, p1;
            p0.h = pk(acc[0] + b4.x, acc[1] + b4.y);
            p1.h = pk(acc[2] + b4.z, acc[3] + b4.w);
            uint2 st; st.x = p0.u; st.y = p1.u;
            *(uint2*)&bufA[m * TOKPAD + h * 32 + (jj >> 1)] = st;
        }
    }
    __syncthreads();   // #3: v ready

    __fp16* resL = (__fp16*)kT;            // res overlay: kT rows are wave-private

    // ---- consumer: 4 tokens in 2 interleaved pairs (named q fragments)
    CONSUME2(w * 4 + 0, uq0, w * 4 + 1, uq1);
    CONSUME2(w * 4 + 2, uq2, w * 4 + 3, uq3);
    __syncthreads();   // #4: all 16 tokens' res in LDS -> out phase

    // ---- out phase: wave w computes out cols w*16..w*16+15 for 16 tokens.
    {
        floatx4 oacc = (floatx4){0.f, 0.f, 0.f, 0.f};
        const __fp16* rrow = resL + (size_t)m * 520 + quad * 8;   // token m
        const __fp16* wrow = wuh + (size_t)(w * 16 + m) * HHE + quad * 8;
        #pragma unroll
        for (int kc = 0; kc < 16; ++kc) {              // K=512 in 32-chunks
            const half8 bf = *(const half8*)(rrow + kc * 32);
            const half8 af = *(const half8*)(wrow + kc * 32);
            oacc = __builtin_amdgcn_mfma_f32_16x16x32_f16(af, bf, oacc, 0, 0, 0);
        }
        const int tok = tok0 + m;
        const int col = w * 16 + quad * 4;             // 4 consecutive out cols
        const float4 b4 = *(const float4*)&bu[col];
        float4 o;
        o.x = oacc[0] + b4.x;
        o.y = oacc[1] + b4.y;
        o.z = oacc[2] + b4.z;
        o.w = oacc[3] + b4.w;
        *(float4*)&out[(size_t)tok * 64 + col] = o;
    }
}

// ---------------------------------------------------------------------------
extern "C" void kernel_launch(void* const* d_in, const int* in_sizes, int n_in,
                              void* d_out, int out_size, void* d_ws, size_t ws_size,
                              hipStream_t stream)
{
    const float* x     = (const float*)d_in[0];
    const float* alpha = (const float*)d_in[1];
    const float* Wk    = (const float*)d_in[2];
    const float* bk    = (const float*)d_in[3];
    const float* Wq    = (const float*)d_in[4];
    const float* bq    = (const float*)d_in[5];
    const float* Wv    = (const float*)d_in[6];
    const float* bv    = (const float*)d_in[7];
    const float* Wu    = (const float*)d_in[8];
    const float* bu    = (const float*)d_in[9];
    float* out = (float*)d_out;

    // workspace (fp16 units): wkh/wqh/wvh/wuh 32768 each
    __fp16* wkh  = (__fp16*)d_ws;
    __fp16* wqh  = wkh + (size_t)HHE * EDIM;
    __fp16* wvh  = wqh + (size_t)HHE * EDIM;
    __fp16* wuh  = wvh + (size_t)HHE * EDIM;

    cvt_fp16_kernel<<<dim3(16, 4), 256, 0, stream>>>(
        Wk, Wq, Wv, Wu, wkh, wqh, wvh, wuh, alpha);
    qkv_attn_out_kernel<<<NTOK / TPB, 256, 0, stream>>>(
        x, wkh, bk, wqh, bq, wvh, bv, wuh, bu, out, alpha);
}